// Round 12
// baseline (167.669 us; speedup 1.0000x reference)
//
#include <hip/hip_runtime.h>
#include <hip/hip_bf16.h>

#define NN   12800
#define TT   20
#define HID  128
#define SPB  16     // seqs per block

typedef __attribute__((ext_vector_type(8))) short          bf16x8;
typedef __attribute__((ext_vector_type(8))) unsigned short ushort8;
typedef __attribute__((ext_vector_type(4))) float          f32x4;
typedef __attribute__((ext_vector_type(4))) unsigned int   uint32x4;

#define L2E 1.4426950408889634f
#define K2  2.8853900817779268f   // 2*log2(e)

// proj table (scaled), unit-grouped layout:
// slot(q, u) = (u&3)*128 + (u>>4)*16 + ((u>>2)&3)*4 + q     (q = gate type, u = unit)
// g_projV[(d*512+v)*512 + slot] = sc * (bias[q*128+u] + sum_e Wih[q*128+u][e]*embed[v][e])
__device__ float g_projV[2 * 512 * 512];
// Whh packed as MFMA *A* fragments (bf16 bits, scaled):
// A-tile nt covers gate-rows r=0..15 -> gate type q=r&3, unit=(nt*4+(r>>2))*4+w
// k-columns permuted to match h-LDS pos order: unit_at_pos(p)=((p&7)*4+(p>>5))*4+((p>>3)&3)
__device__ __align__(16) unsigned short g_Apk[2 * 4 * 8 * 4 * 64 * 8];

__device__ __forceinline__ unsigned short f2bf(float f) {
    union { float f; unsigned u; } a; a.f = f;
    unsigned r = a.u + 0x7FFF + ((a.u >> 16) & 1);
    return (unsigned short)(r >> 16);
}
__device__ __forceinline__ float ex2(float x) {   // 2^x, raw v_exp_f32
#if __has_builtin(__builtin_amdgcn_exp2f)
    return __builtin_amdgcn_exp2f(x);
#else
    float r; asm("v_exp_f32 %0, %1" : "=v"(r) : "v"(x)); return r;
#endif
}

// ---- prep 1: char -> scaled gate-preact table; 4 chars per block ----
__global__ __launch_bounds__(512) void prep_proj(
    const float* __restrict__ embed,
    const float* __restrict__ Wih_f, const float* __restrict__ b_f,
    const float* __restrict__ Wih_b, const float* __restrict__ b_b)
{
    const int vg = blockIdx.x;   // group of 4 chars
    const int d  = blockIdx.y;
    const int g  = threadIdx.x;  // gate row 0..511
    __shared__ __align__(16) float ev[4][HID];
    ev[g >> 7][g & 127] = embed[(vg * 4 + (g >> 7)) * HID + (g & 127)];
    __syncthreads();
    const float* Wi = d ? Wih_b : Wih_f;
    const float* bb = d ? b_b : b_f;
    const f32x4* Wrow = reinterpret_cast<const f32x4*>(Wi + g * HID);
    float acc[4] = {0.f, 0.f, 0.f, 0.f};
    #pragma unroll 8
    for (int k4 = 0; k4 < 32; ++k4) {
        const f32x4 wv = Wrow[k4];
        #pragma unroll
        for (int j = 0; j < 4; ++j) {
            acc[0] = fmaf(wv[j], ev[0][k4 * 4 + j], acc[0]);
            acc[1] = fmaf(wv[j], ev[1][k4 * 4 + j], acc[1]);
            acc[2] = fmaf(wv[j], ev[2][k4 * 4 + j], acc[2]);
            acc[3] = fmaf(wv[j], ev[3][k4 * 4 + j], acc[3]);
        }
    }
    const int q = g >> 7, u = g & 127;
    const float sc = (q == 2) ? K2 : L2E;
    const float bv = bb[g];
    const int slot = (u & 3) * 128 + (u >> 4) * 16 + ((u >> 2) & 3) * 4 + q;
    #pragma unroll
    for (int v = 0; v < 4; ++v)
        g_projV[(d * 512 + vg * 4 + v) * 512 + slot] = (bv + acc[v]) * sc;
}

// ---- prep 2: pack scaled Whh into A fragments ----
__global__ void prep_apack(const float* __restrict__ Whh_f, const float* __restrict__ Whh_b)
{
    const int id = blockIdx.x * 256 + threadIdx.x;   // 0..16383
    const int lane = id & 63;
    const int kt   = (id >> 6) & 3;
    const int nt   = (id >> 8) & 7;
    const int w    = (id >> 11) & 3;
    const int d    = id >> 13;
    const int r    = lane & 15;       // A-tile gate row
    const int rgl  = lane >> 4;
    const float* Wh = d ? Whh_b : Whh_f;
    const int q    = r & 3;
    const int unit = (nt * 4 + (r >> 2)) * 4 + w;
    const int row  = q * 128 + unit;  // original Whh row
    const float sc = (q == 2) ? K2 : L2E;
    ushort8 o;
    #pragma unroll
    for (int i = 0; i < 8; ++i) {
        const int p = kt * 32 + rgl * 8 + i;   // k position (pos-order)
        const int col = ((p & 7) * 4 + (p >> 5)) * 4 + ((p >> 3) & 3);  // unit at pos p
        o[i] = f2bf(Wh[row * HID + col] * sc);
    }
    reinterpret_cast<ushort8*>(g_Apk)[id] = o;
}

// one LSTM step. acc[] preloaded with proj(tc); ends with gather of proj(tn) into acc.
#define STEP(tc, tn, HC, HN)                                                  \
{                                                                             \
    bf16x8 Bh[4];                                                             \
    _Pragma("unroll")                                                         \
    for (int kt = 0; kt < 4; ++kt)                                            \
        Bh[kt] = *reinterpret_cast<const bf16x8*>(&HC[c0 * 136 + kt * 32 + rg * 8]); \
    _Pragma("unroll")                                                         \
    for (int kt = 0; kt < 4; ++kt) {                                          \
        _Pragma("unroll")                                                     \
        for (int nt = 0; nt < 8; ++nt)                                        \
            acc[nt] = __builtin_amdgcn_mfma_f32_16x16x32_bf16(Awh[nt][kt], Bh[kt], acc[nt], 0, 0, 0); \
    }                                                                         \
    const bool valid = ((tc) < len_c);                                        \
    _Pragma("unroll")                                                         \
    for (int nt = 0; nt < 8; ++nt) {                                          \
        const float ei = ex2(-acc[nt][0]);                                    \
        const float ef = ex2(-acc[nt][1]);                                    \
        const float tg = ex2(-acc[nt][2]);                                    \
        const float eo = ex2(-acc[nt][3]);                                    \
        const float rf = __builtin_amdgcn_rcpf(1.0f + ef);                    \
        const float rr = __builtin_amdgcn_rcpf((1.0f + ei) * (1.0f + tg));    \
        const float cn = fmaf(rf, cst[nt], fmaf(-K2, tg, K2) * rr);           \
        const float ec = ex2(-cn);                                            \
        const float r2 = __builtin_amdgcn_rcpf((1.0f + eo) * (1.0f + ec));    \
        const float hn = (1.0f - ec) * r2;                                    \
        cst[nt]  = valid ? cn : cst[nt];                                      \
        hreg[nt] = valid ? hn : hreg[nt];                                     \
    }                                                                         \
    {                                                                         \
        unsigned h0w, h1w, h2w, h3w;                                          \
        asm("v_cvt_pk_bf16_f32 %0, %1, %2" : "=v"(h0w) : "v"(hreg[0]), "v"(hreg[1])); \
        asm("v_cvt_pk_bf16_f32 %0, %1, %2" : "=v"(h1w) : "v"(hreg[2]), "v"(hreg[3])); \
        asm("v_cvt_pk_bf16_f32 %0, %1, %2" : "=v"(h2w) : "v"(hreg[4]), "v"(hreg[5])); \
        asm("v_cvt_pk_bf16_f32 %0, %1, %2" : "=v"(h3w) : "v"(hreg[6]), "v"(hreg[7])); \
        const uint32x4 hv = {h0w, h1w, h2w, h3w};                             \
        *reinterpret_cast<uint32x4*>(&HN[c0 * 136 + (rg * 4 + w) * 8]) = hv;  \
    }                                                                         \
    {                                                                         \
        const int ch = chars[c0 * TT + (tn)];                                 \
        const f32x4* p = reinterpret_cast<const f32x4*>(                      \
            g_projV + (dir * 512 + ch) * 512 + w * 128 + rg * 4);             \
        _Pragma("unroll")                                                     \
        for (int nt = 0; nt < 8; ++nt) acc[nt] = p[nt * 4];                   \
    }                                                                         \
    __syncthreads();                                                          \
}

// ---- main: 16 seqs/block, 4 waves; wave w owns units u==w (mod 4) ----
__global__ __launch_bounds__(256, 2) void lstm_swp(
    const int* __restrict__ x, float* __restrict__ out)
{
    __shared__ __align__(16) unsigned short h0[SPB * 136];  // bf16 h ping (pos-order units)
    __shared__ __align__(16) unsigned short h1[SPB * 136];  // bf16 h pong
    __shared__ int chars[SPB * TT];
    __shared__ int len_sh[SPB];

    const int tid  = threadIdx.x;
    const int lane = tid & 63;
    const int w    = tid >> 6;         // wave id 0..3
    const int c0   = lane & 15;        // this lane's sequence (B col / D col)
    const int rg   = lane >> 4;        // row group
    const int dir  = blockIdx.y;
    const int n0   = blockIdx.x * SPB;

    for (int i = tid; i < SPB * TT; i += 256) chars[i] = x[n0 * TT + i];
    for (int i = tid; i < SPB * 136; i += 256) { h0[i] = 0; h1[i] = 0; }
    __syncthreads();
    if (tid < SPB) {
        int l = 0;
        #pragma unroll
        for (int t = 0; t < TT; ++t) l += (chars[tid * TT + t] > 0) ? 1 : 0;
        len_sh[tid] = l;
    }

    // resident Whh A-fragments: 8 gate-row tiles x 4 k-frags
    bf16x8 Awh[8][4];
    {
        const bf16x8* Ap = reinterpret_cast<const bf16x8*>(g_Apk);
        #pragma unroll
        for (int nt = 0; nt < 8; ++nt)
            #pragma unroll
            for (int kt = 0; kt < 4; ++kt)
                Awh[nt][kt] = Ap[((((dir * 4 + w) * 8 + nt) * 4 + kt) * 64) + lane];
    }
    // preload proj for first step into acc (C-init)
    f32x4 acc[8];
    {
        const int tfirst = dir ? (TT - 1) : 0;
        // chars visible after the sync above
        const int ch = chars[c0 * TT + tfirst];
        const f32x4* p = reinterpret_cast<const f32x4*>(
            g_projV + (dir * 512 + ch) * 512 + w * 128 + rg * 4);
        #pragma unroll
        for (int nt = 0; nt < 8; ++nt) acc[nt] = p[nt * 4];
    }
    __syncthreads();

    const int len_c = len_sh[c0];

    float cst[8]  = {};   // scaled cell state (K2*c), one per owned unit
    float hreg[8] = {};   // fp32 h for final output

    for (int step = 0; step < TT; step += 2) {
        const int t0 = dir ? (TT - 1 - step) : step;
        const int t1 = dir ? (TT - 2 - step) : (step + 1);
        const int t2 = (step + 2 < TT) ? (dir ? (TT - 3 - step) : (step + 2)) : 0;
        STEP(t0, t1, h0, h1)
        STEP(t1, t2, h1, h0)
    }

    // lane's 8 units: u = (nt*4 + rg)*4 + w, seq = c0
    #pragma unroll
    for (int nt = 0; nt < 8; ++nt)
        out[(n0 + c0) * 256 + dir * 128 + (nt * 4 + rg) * 4 + w] = hreg[nt];
}

extern "C" void kernel_launch(void* const* d_in, const int* in_sizes, int n_in,
                              void* d_out, int out_size, void* d_ws, size_t ws_size,
                              hipStream_t stream)
{
    const int*   x     = (const int*)  d_in[0];
    const float* embed = (const float*)d_in[1];
    const float* Wih_f = (const float*)d_in[2];
    const float* Whh_f = (const float*)d_in[3];
    const float* b_f   = (const float*)d_in[4];
    const float* Wih_b = (const float*)d_in[5];
    const float* Whh_b = (const float*)d_in[6];
    const float* b_b   = (const float*)d_in[7];
    float* out = (float*)d_out;

    prep_proj <<<dim3(128, 2), 512, 0, stream>>>(embed, Wih_f, b_f, Wih_b, b_b);
    prep_apack<<<64, 256, 0, stream>>>(Whh_f, Whh_b);
    lstm_swp  <<<dim3(NN / SPB, 2), 256, 0, stream>>>(x, out);
}